// Round 3
// baseline (353.365 us; speedup 1.0000x reference)
//
#include <hip/hip_runtime.h>

#define NS 64     // samples per batch
#define D  256    // hidden dims
#define O  10     // output dim
#define TK 64     // GEMM K-chunk (single-stage per block: K-slice == TK)
#define LSTR 68   // LDS row stride (TK + 4 pad: 16B aligned)

// ---------------- prep1: forward passes (blocks 0..127, 512 thr, k-split-2)
// ----------------        + W2 transpose (128..191) + out zeroing (192..255) ----
__global__ __launch_bounds__(512) void prep1_kernel(
    const float* __restrict__ x1, const float* __restrict__ x2,
    const float* __restrict__ W1, const float* __restrict__ b1,
    const float* __restrict__ W2, const float* __restrict__ b2,
    const float* __restrict__ W3,
    float* __restrict__ h1o, float* __restrict__ S1o,
    float* __restrict__ h2o, float* __restrict__ G2L,
    float* __restrict__ W2T, float* __restrict__ out)
{
    int t = threadIdx.x;
    if (blockIdx.x >= 192) {
        // zero out[64*64*10*10] = 409600 floats = 102400 float4, 64 blocks x 512 thr
        int idx = (blockIdx.x - 192) * 512 + t;       // 0..32767
        float4* o4 = (float4*)out;
        #pragma unroll
        for (int u = 0; u < 4; ++u) {
            int e = idx + u * 32768;
            if (e < 102400) o4[e] = make_float4(0.f, 0.f, 0.f, 0.f);
        }
        return;
    }
    if (blockIdx.x >= 128) {
        // W2 transpose: 64 blocks, 32x32 tiles, 512 threads (16 rows/pass x 2)
        int blk = blockIdx.x - 128;
        int bxT = blk & 7, byT = blk >> 3;
        __shared__ float tile[32][33];
        int txT = t & 31, tyT = t >> 5;        // tyT 0..15
        #pragma unroll
        for (int r = 0; r < 2; ++r)
            tile[tyT + 16 * r][txT] = W2[(byT * 32 + tyT + 16 * r) * D + bxT * 32 + txT];
        __syncthreads();
        #pragma unroll
        for (int r = 0; r < 2; ++r)
            W2T[(bxT * 32 + tyT + 16 * r) * D + byT * 32 + txT] = tile[txT][tyT + 16 * r];
        return;
    }

    // forward: 1 sample per block, 512 threads = (half k-range) x (256 outputs)
    int s = blockIdx.x;
    const float* x = (s < NS) ? (x1 + s * D) : (x2 + (s - NS) * D);
    int tt = t & 255, half = t >> 8;
    int k0 = half * 128;
    __shared__ float xs[D];
    __shared__ float hs[D];
    __shared__ float part[2][D];

    if (half == 0) xs[tt] = x[tt];
    __syncthreads();

    float acc = half ? 0.0f : b1[tt];
    #pragma unroll 8
    for (int k = 0; k < 128; ++k) acc = fmaf(xs[k0 + k], W1[(k0 + k) * D + tt], acc);
    part[half][tt] = acc;
    __syncthreads();

    if (half == 0) {
        float h1v = tanhf(part[0][tt] + part[1][tt]);
        h1o[s * D + tt] = h1v;
        S1o[s * D + tt] = 1.0f - h1v * h1v;
        hs[tt] = h1v;
    }
    __syncthreads();

    acc = half ? 0.0f : b2[tt];
    #pragma unroll 8
    for (int k = 0; k < 128; ++k) acc = fmaf(hs[k0 + k], W2[(k0 + k) * D + tt], acc);
    part[half][tt] = acc;
    __syncthreads();

    if (half == 0) {
        float h2v = tanhf(part[0][tt] + part[1][tt]);
        h2o[s * D + tt] = h2v;
        hs[tt] = 1.0f - h2v * h2v;             // reuse hs for s2 (all hs reads done)
    }
    __syncthreads();

    // G2 in [s][a][i] layout (K-contiguous rows for the GEMM); all 512 threads
    for (int idx = t; idx < O * D; idx += 512) {
        int a = idx >> 8, i = idx & 255;
        G2L[(s * O + a) * D + i] = hs[i] * W3[i * O + a];
    }
}

// ---------------- prep2: backward G1 (blocks 0..127, 512 thr, j-split-2)
// ----------------        + dot matrices (blocks 128..319) ----------------------
__global__ __launch_bounds__(512) void prep2_kernel(
    const float* __restrict__ W2T, const float* __restrict__ S1,
    const float* __restrict__ G2L, float* __restrict__ G1L,
    const float* __restrict__ x1, const float* __restrict__ x2,
    const float* __restrict__ h1, const float* __restrict__ h2,
    float* __restrict__ dots)
{
    int t = threadIdx.x;
    if (blockIdx.x < 128) {
        int s = blockIdx.x;
        __shared__ float g2s[O * D];           // [a][j], 10 KB
        __shared__ float red[O * D];           // half-1 partials, 10 KB
        for (int idx = t; idx < D * O; idx += 512) g2s[idx] = G2L[s * D * O + idx];
        __syncthreads();

        int tt = t & 255, half = t >> 8;
        int j0 = half * 128;
        float acc[O];
        #pragma unroll
        for (int a = 0; a < O; ++a) acc[a] = 0.0f;
        // j-loop vectorized: g2 via ds_read_b128 (4 j at once) -> ~2x lower LDS issue
        #pragma unroll 2
        for (int j = 0; j < 128; j += 4) {
            float w0 = W2T[(j0 + j + 0) * D + tt];  // coalesced across tt
            float w1 = W2T[(j0 + j + 1) * D + tt];
            float w2 = W2T[(j0 + j + 2) * D + tt];
            float w3 = W2T[(j0 + j + 3) * D + tt];
            #pragma unroll
            for (int a = 0; a < O; ++a) {
                float4 g = *(const float4*)&g2s[a * D + j0 + j];
                acc[a] = fmaf(w0, g.x, acc[a]);
                acc[a] = fmaf(w1, g.y, acc[a]);
                acc[a] = fmaf(w2, g.z, acc[a]);
                acc[a] = fmaf(w3, g.w, acc[a]);
            }
        }
        if (half == 1) {
            #pragma unroll
            for (int a = 0; a < O; ++a) red[a * D + tt] = acc[a];
        }
        __syncthreads();
        if (half == 0) {
            float s1 = S1[s * D + tt];
            #pragma unroll
            for (int a = 0; a < O; ++a)
                G1L[(s * O + a) * D + tt] = s1 * (acc[a] + red[a * D + tt]);
        }
        return;
    }

    // dots: 192 blocks: which = idx>>6, n = idx&63; 8 waves per block
    int idx = blockIdx.x - 128;
    int which = idx >> 6, n = idx & 63;
    const float* A; const float* B;
    if (which == 0)      { A = x1 + n * D; B = x2; }
    else if (which == 1) { A = h1 + n * D; B = h1 + NS * D; }
    else                 { A = h2 + n * D; B = h2 + NS * D; }
    __shared__ float as[D];
    if (t < D) as[t] = A[t];
    __syncthreads();
    int wave = t >> 6, lane = t & 63;
    for (int m = wave; m < NS; m += 8) {
        const float* Bv = B + m * D;
        float v = as[lane] * Bv[lane]
                + as[64 + lane] * Bv[64 + lane]
                + as[128 + lane] * Bv[128 + lane]
                + as[192 + lane] * Bv[192 + lane];
        #pragma unroll
        for (int off = 32; off > 0; off >>= 1) v += __shfl_xor(v, off);
        if (lane == 0) dots[(which * NS + n) * NS + m] = v;
    }
}

// ---------------- dual 640x640x256 GEMM, K-split-4, atomic NTK epilogue --------
// 100 tiles (64x64) x 4 K-slices = 400 blocks. Single TK=64 stage: 2 barriers total.
// Scaled contributions are atomically added to out (cx*ΣP1_ks == Σcx*P1_ks).
__global__ __launch_bounds__(256) void ntk_gemm_kernel(
    const float* __restrict__ G1L, const float* __restrict__ G2L,
    const float* __restrict__ dots, float* __restrict__ out)
{
    int tile = blockIdx.x % 100;
    int ks   = blockIdx.x / 100;                      // 0..3, K-slice of 64
    int by = tile / 10, bx = tile % 10;               // 64x64 output tile
    __shared__ float A1[64 * LSTR], B1[64 * LSTR], A2[64 * LSTR], B2[64 * LSTR]; // ~69.6 KB
    int t = threadIdx.x;
    int tx = t & 15, ty = t >> 4;

    float acc1[4][4], acc2[4][4];
    #pragma unroll
    for (int i = 0; i < 4; ++i)
        #pragma unroll
        for (int j = 0; j < 4; ++j) { acc1[i][j] = 0.0f; acc2[i][j] = 0.0f; }

    const float* arow1 = G1L + (by * 64) * D + ks * 64;
    const float* brow1 = G1L + (640 + bx * 64) * D + ks * 64;
    const float* arow2 = G2L + (by * 64) * D + ks * 64;
    const float* brow2 = G2L + (640 + bx * 64) * D + ks * 64;

    // stage 4 tiles of 64x64 floats; 1024 float4 each; 4 float4/thread/tile
    #pragma unroll
    for (int u = 0; u < 4; ++u) {
        int idx = t + u * 256;
        int r = idx >> 4, c4 = idx & 15;
        int goff = r * D + c4 * 4;
        int loff = r * LSTR + c4 * 4;
        *(float4*)&A1[loff] = *(const float4*)&arow1[goff];
        *(float4*)&B1[loff] = *(const float4*)&brow1[goff];
        *(float4*)&A2[loff] = *(const float4*)&arow2[goff];
        *(float4*)&B2[loff] = *(const float4*)&brow2[goff];
    }
    __syncthreads();

    #pragma unroll
    for (int kk = 0; kk < TK; kk += 4) {
        float4 a1[4], b1v[4], a2[4], b2v[4];
        #pragma unroll
        for (int i = 0; i < 4; ++i) {
            a1[i] = *(const float4*)&A1[(4 * ty + i) * LSTR + kk];
            a2[i] = *(const float4*)&A2[(4 * ty + i) * LSTR + kk];
        }
        #pragma unroll
        for (int j = 0; j < 4; ++j) {
            b1v[j] = *(const float4*)&B1[(tx + 16 * j) * LSTR + kk];
            b2v[j] = *(const float4*)&B2[(tx + 16 * j) * LSTR + kk];
        }
        #pragma unroll
        for (int i = 0; i < 4; ++i)
            #pragma unroll
            for (int j = 0; j < 4; ++j) {
                acc1[i][j] = fmaf(a1[i].x, b1v[j].x, acc1[i][j]);
                acc1[i][j] = fmaf(a1[i].y, b1v[j].y, acc1[i][j]);
                acc1[i][j] = fmaf(a1[i].z, b1v[j].z, acc1[i][j]);
                acc1[i][j] = fmaf(a1[i].w, b1v[j].w, acc1[i][j]);
                acc2[i][j] = fmaf(a2[i].x, b2v[j].x, acc2[i][j]);
                acc2[i][j] = fmaf(a2[i].y, b2v[j].y, acc2[i][j]);
                acc2[i][j] = fmaf(a2[i].z, b2v[j].z, acc2[i][j]);
                acc2[i][j] = fmaf(a2[i].w, b2v[j].w, acc2[i][j]);
            }
    }

    // epilogue: out[n,m,a,b] += cx*P1_ks + ch1*P2_ks (+ diag consts, once via ks==0)
    #pragma unroll
    for (int i = 0; i < 4; ++i) {
        int R = by * 64 + 4 * ty + i;
        int n = R / 10, a = R - n * 10;
        #pragma unroll
        for (int j = 0; j < 4; ++j) {
            int C = bx * 64 + tx + 16 * j;
            int m = C / 10, b = C - m * 10;
            float cx  = 1.0f + dots[0 * NS * NS + n * NS + m];
            float ch1 = 1.0f + dots[1 * NS * NS + n * NS + m];
            float val = cx * acc1[i][j] + ch1 * acc2[i][j];
            if (ks == 0 && a == b) val += 1.0f + dots[2 * NS * NS + n * NS + m];
            atomicAdd(&out[(n * NS + m) * (O * O) + a * O + b], val);
        }
    }
}

extern "C" void kernel_launch(void* const* d_in, const int* in_sizes, int n_in,
                              void* d_out, int out_size, void* d_ws, size_t ws_size,
                              hipStream_t stream) {
    const float* x1 = (const float*)d_in[0];
    const float* x2 = (const float*)d_in[1];
    const float* W1 = (const float*)d_in[2];
    const float* b1 = (const float*)d_in[3];
    const float* W2 = (const float*)d_in[4];
    const float* b2 = (const float*)d_in[5];
    const float* W3 = (const float*)d_in[6];
    // b3 (d_in[7]) does not enter the Jacobian.

    float* ws   = (float*)d_ws;
    float* h1   = ws;                     // 128*256
    float* S1   = h1 + 128 * D;           // 128*256
    float* h2   = S1 + 128 * D;           // 128*256
    float* G2L  = h2 + 128 * D;           // 1280*256  ([s*O+a][i])
    float* G1L  = G2L + 1280 * D;         // 1280*256
    float* W2T  = G1L + 1280 * D;         // 256*256
    float* dots = W2T + D * D;            // 3*64*64
    float* out  = (float*)d_out;

    hipLaunchKernelGGL(prep1_kernel, dim3(256), dim3(512), 0, stream,
                       x1, x2, W1, b1, W2, b2, W3, h1, S1, h2, G2L, W2T, out);
    hipLaunchKernelGGL(prep2_kernel, dim3(320), dim3(512), 0, stream,
                       W2T, S1, G2L, G1L, x1, x2, h1, h2, dots);
    hipLaunchKernelGGL(ntk_gemm_kernel, dim3(400), dim3(256), 0, stream,
                       G1L, G2L, dots, out);
}

// Round 4
// 116.110 us; speedup vs baseline: 3.0434x; 3.0434x over previous
//
#include <hip/hip_runtime.h>

#define NS 64     // samples per batch
#define D  256    // hidden dims
#define O  10     // output dim
#define TK 64     // GEMM K-chunk (single-stage per block: K-slice == TK)
#define LSTR 68   // LDS row stride (TK + 4 pad: 16B aligned)

// ---------------- prep1: forward passes (blocks 0..127, 512 thr, k-split-2)
// ----------------        + W2 transpose (blocks 128..191) ----------------------
__global__ __launch_bounds__(512) void prep1_kernel(
    const float* __restrict__ x1, const float* __restrict__ x2,
    const float* __restrict__ W1, const float* __restrict__ b1,
    const float* __restrict__ W2, const float* __restrict__ b2,
    const float* __restrict__ W3,
    float* __restrict__ h1o, float* __restrict__ S1o,
    float* __restrict__ h2o, float* __restrict__ G2L,
    float* __restrict__ W2T)
{
    int t = threadIdx.x;
    if (blockIdx.x >= 128) {
        // W2 transpose: 64 blocks, 32x32 tiles, 512 threads (16 rows/pass x 2)
        int blk = blockIdx.x - 128;
        int bxT = blk & 7, byT = blk >> 3;
        __shared__ float tile[32][33];
        int txT = t & 31, tyT = t >> 5;        // tyT 0..15
        #pragma unroll
        for (int r = 0; r < 2; ++r)
            tile[tyT + 16 * r][txT] = W2[(byT * 32 + tyT + 16 * r) * D + bxT * 32 + txT];
        __syncthreads();
        #pragma unroll
        for (int r = 0; r < 2; ++r)
            W2T[(bxT * 32 + tyT + 16 * r) * D + byT * 32 + txT] = tile[txT][tyT + 16 * r];
        return;
    }

    // forward: 1 sample per block, 512 threads = (half k-range) x (256 outputs)
    int s = blockIdx.x;
    const float* x = (s < NS) ? (x1 + s * D) : (x2 + (s - NS) * D);
    int tt = t & 255, half = t >> 8;
    int k0 = half * 128;
    __shared__ float xs[D];
    __shared__ float hs[D];
    __shared__ float part[2][D];

    if (half == 0) xs[tt] = x[tt];
    __syncthreads();

    float acc = half ? 0.0f : b1[tt];
    #pragma unroll 8
    for (int k = 0; k < 128; ++k) acc = fmaf(xs[k0 + k], W1[(k0 + k) * D + tt], acc);
    part[half][tt] = acc;
    __syncthreads();

    if (half == 0) {
        float h1v = tanhf(part[0][tt] + part[1][tt]);
        h1o[s * D + tt] = h1v;
        S1o[s * D + tt] = 1.0f - h1v * h1v;
        hs[tt] = h1v;
    }
    __syncthreads();

    acc = half ? 0.0f : b2[tt];
    #pragma unroll 8
    for (int k = 0; k < 128; ++k) acc = fmaf(hs[k0 + k], W2[(k0 + k) * D + tt], acc);
    part[half][tt] = acc;
    __syncthreads();

    if (half == 0) {
        float h2v = tanhf(part[0][tt] + part[1][tt]);
        h2o[s * D + tt] = h2v;
        hs[tt] = 1.0f - h2v * h2v;             // reuse hs for s2 (all hs reads done)
    }
    __syncthreads();

    // G2 in [s][a][i] layout (K-contiguous rows for the GEMM); all 512 threads
    for (int idx = t; idx < O * D; idx += 512) {
        int a = idx >> 8, i = idx & 255;
        G2L[(s * O + a) * D + i] = hs[i] * W3[i * O + a];
    }
}

// ---------------- prep2: backward G1 (blocks 0..127, 512 thr, j-split-2)
// ----------------        + dot matrices (blocks 128..319) ----------------------
__global__ __launch_bounds__(512) void prep2_kernel(
    const float* __restrict__ W2T, const float* __restrict__ S1,
    const float* __restrict__ G2L, float* __restrict__ G1L,
    const float* __restrict__ x1, const float* __restrict__ x2,
    const float* __restrict__ h1, const float* __restrict__ h2,
    float* __restrict__ dots)
{
    int t = threadIdx.x;
    if (blockIdx.x < 128) {
        int s = blockIdx.x;
        __shared__ float g2s[O * D];           // [a][j], 10 KB
        __shared__ float red[O * D];           // half-1 partials, 10 KB
        for (int idx = t; idx < D * O; idx += 512) g2s[idx] = G2L[s * D * O + idx];
        __syncthreads();

        int tt = t & 255, half = t >> 8;
        int j0 = half * 128;
        float acc[O];
        #pragma unroll
        for (int a = 0; a < O; ++a) acc[a] = 0.0f;
        // j-loop vectorized: g2 via ds_read_b128 (4 j at once) -> ~2x lower LDS issue
        #pragma unroll 2
        for (int j = 0; j < 128; j += 4) {
            float w0 = W2T[(j0 + j + 0) * D + tt];  // coalesced across tt
            float w1 = W2T[(j0 + j + 1) * D + tt];
            float w2 = W2T[(j0 + j + 2) * D + tt];
            float w3 = W2T[(j0 + j + 3) * D + tt];
            #pragma unroll
            for (int a = 0; a < O; ++a) {
                float4 g = *(const float4*)&g2s[a * D + j0 + j];
                acc[a] = fmaf(w0, g.x, acc[a]);
                acc[a] = fmaf(w1, g.y, acc[a]);
                acc[a] = fmaf(w2, g.z, acc[a]);
                acc[a] = fmaf(w3, g.w, acc[a]);
            }
        }
        if (half == 1) {
            #pragma unroll
            for (int a = 0; a < O; ++a) red[a * D + tt] = acc[a];
        }
        __syncthreads();
        if (half == 0) {
            float s1 = S1[s * D + tt];
            #pragma unroll
            for (int a = 0; a < O; ++a)
                G1L[(s * O + a) * D + tt] = s1 * (acc[a] + red[a * D + tt]);
        }
        return;
    }

    // dots: 192 blocks: which = idx>>6, n = idx&63; 8 waves per block
    int idx = blockIdx.x - 128;
    int which = idx >> 6, n = idx & 63;
    const float* A; const float* B;
    if (which == 0)      { A = x1 + n * D; B = x2; }
    else if (which == 1) { A = h1 + n * D; B = h1 + NS * D; }
    else                 { A = h2 + n * D; B = h2 + NS * D; }
    __shared__ float as[D];
    if (t < D) as[t] = A[t];
    __syncthreads();
    int wave = t >> 6, lane = t & 63;
    for (int m = wave; m < NS; m += 8) {
        const float* Bv = B + m * D;
        float v = as[lane] * Bv[lane]
                + as[64 + lane] * Bv[64 + lane]
                + as[128 + lane] * Bv[128 + lane]
                + as[192 + lane] * Bv[192 + lane];
        #pragma unroll
        for (int off = 32; off > 0; off >>= 1) v += __shfl_xor(v, off);
        if (lane == 0) dots[(which * NS + n) * NS + m] = v;
    }
}

// ---------------- dual 640x640x256 GEMM, K-split-4 into partial buffers --------
// 100 tiles (64x64) x 4 K-slices = 400 blocks. Single TK=64 stage: 1 barrier total.
__global__ __launch_bounds__(256) void ntk_gemm_kernel(
    const float* __restrict__ G1L, const float* __restrict__ G2L,
    float* __restrict__ P1p, float* __restrict__ P2p)
{
    int tile = blockIdx.x % 100;
    int ks   = blockIdx.x / 100;                      // 0..3, K-slice of 64
    int by = tile / 10, bx = tile % 10;               // 64x64 output tile
    __shared__ float A1[64 * LSTR], B1[64 * LSTR], A2[64 * LSTR], B2[64 * LSTR]; // ~69.6 KB
    int t = threadIdx.x;
    int tx = t & 15, ty = t >> 4;

    float acc1[4][4], acc2[4][4];
    #pragma unroll
    for (int i = 0; i < 4; ++i)
        #pragma unroll
        for (int j = 0; j < 4; ++j) { acc1[i][j] = 0.0f; acc2[i][j] = 0.0f; }

    const float* arow1 = G1L + (by * 64) * D + ks * 64;
    const float* brow1 = G1L + (640 + bx * 64) * D + ks * 64;
    const float* arow2 = G2L + (by * 64) * D + ks * 64;
    const float* brow2 = G2L + (640 + bx * 64) * D + ks * 64;

    // stage 4 tiles of 64x64 floats; 1024 float4 each; 4 float4/thread/tile
    #pragma unroll
    for (int u = 0; u < 4; ++u) {
        int idx = t + u * 256;
        int r = idx >> 4, c4 = idx & 15;
        int goff = r * D + c4 * 4;
        int loff = r * LSTR + c4 * 4;
        *(float4*)&A1[loff] = *(const float4*)&arow1[goff];
        *(float4*)&B1[loff] = *(const float4*)&brow1[goff];
        *(float4*)&A2[loff] = *(const float4*)&arow2[goff];
        *(float4*)&B2[loff] = *(const float4*)&brow2[goff];
    }
    __syncthreads();

    #pragma unroll
    for (int kk = 0; kk < TK; kk += 4) {
        float4 a1[4], b1v[4], a2[4], b2v[4];
        #pragma unroll
        for (int i = 0; i < 4; ++i) {
            a1[i] = *(const float4*)&A1[(4 * ty + i) * LSTR + kk];
            a2[i] = *(const float4*)&A2[(4 * ty + i) * LSTR + kk];
        }
        #pragma unroll
        for (int j = 0; j < 4; ++j) {
            b1v[j] = *(const float4*)&B1[(tx + 16 * j) * LSTR + kk];
            b2v[j] = *(const float4*)&B2[(tx + 16 * j) * LSTR + kk];
        }
        #pragma unroll
        for (int i = 0; i < 4; ++i)
            #pragma unroll
            for (int j = 0; j < 4; ++j) {
                acc1[i][j] = fmaf(a1[i].x, b1v[j].x, acc1[i][j]);
                acc1[i][j] = fmaf(a1[i].y, b1v[j].y, acc1[i][j]);
                acc1[i][j] = fmaf(a1[i].z, b1v[j].z, acc1[i][j]);
                acc1[i][j] = fmaf(a1[i].w, b1v[j].w, acc1[i][j]);
                acc2[i][j] = fmaf(a2[i].x, b2v[j].x, acc2[i][j]);
                acc2[i][j] = fmaf(a2[i].y, b2v[j].y, acc2[i][j]);
                acc2[i][j] = fmaf(a2[i].z, b2v[j].z, acc2[i][j]);
                acc2[i][j] = fmaf(a2[i].w, b2v[j].w, acc2[i][j]);
            }
    }

    // store K-slice partials (coalesced per 16-lane group)
    #pragma unroll
    for (int i = 0; i < 4; ++i) {
        int R = by * 64 + 4 * ty + i;
        float* p1row = P1p + (ks * 640 + R) * 640;
        float* p2row = P2p + (ks * 640 + R) * 640;
        #pragma unroll
        for (int j = 0; j < 4; ++j) {
            int C = bx * 64 + tx + 16 * j;
            p1row[C] = acc1[i][j];
            p2row[C] = acc2[i][j];
        }
    }
}

// ---------------- combine: sum 4 K-slices + NTK epilogue ----------------------
__global__ __launch_bounds__(256) void combine_kernel(
    const float* __restrict__ P1p, const float* __restrict__ P2p,
    const float* __restrict__ dots, float* __restrict__ out)
{
    int base = blockIdx.x * 1024;
    #pragma unroll
    for (int u = 0; u < 4; ++u) {
        int e = base + u * 256 + threadIdx.x;    // 0..409599, consecutive C per wave
        int R = e / 640, C = e - R * 640;
        float p1 = 0.0f, p2 = 0.0f;
        #pragma unroll
        for (int s = 0; s < 4; ++s) {
            p1 += P1p[(s * 640 + R) * 640 + C];
            p2 += P2p[(s * 640 + R) * 640 + C];
        }
        int n = R / 10, a = R - n * 10;
        int m = C / 10, b = C - m * 10;
        float cx  = 1.0f + dots[0 * NS * NS + n * NS + m];
        float ch1 = 1.0f + dots[1 * NS * NS + n * NS + m];
        float val = cx * p1 + ch1 * p2;
        if (a == b) val += 1.0f + dots[2 * NS * NS + n * NS + m];
        out[(n * NS + m) * (O * O) + a * O + b] = val;
    }
}

extern "C" void kernel_launch(void* const* d_in, const int* in_sizes, int n_in,
                              void* d_out, int out_size, void* d_ws, size_t ws_size,
                              hipStream_t stream) {
    const float* x1 = (const float*)d_in[0];
    const float* x2 = (const float*)d_in[1];
    const float* W1 = (const float*)d_in[2];
    const float* b1 = (const float*)d_in[3];
    const float* W2 = (const float*)d_in[4];
    const float* b2 = (const float*)d_in[5];
    const float* W3 = (const float*)d_in[6];
    // b3 (d_in[7]) does not enter the Jacobian.

    float* ws   = (float*)d_ws;
    float* h1   = ws;                     // 128*256
    float* S1   = h1 + 128 * D;           // 128*256
    float* h2   = S1 + 128 * D;           // 128*256
    float* G2L  = h2 + 128 * D;           // 1280*256  ([s*O+a][i])
    float* G1L  = G2L + 1280 * D;         // 1280*256
    float* W2T  = G1L + 1280 * D;         // 256*256
    float* dots = W2T + D * D;            // 3*64*64
    float* P1p  = dots + 3 * NS * NS;     // 4*640*640 K-slice partials
    float* P2p  = P1p + 4 * 640 * 640;    // 4*640*640
    float* out  = (float*)d_out;

    hipLaunchKernelGGL(prep1_kernel, dim3(192), dim3(512), 0, stream,
                       x1, x2, W1, b1, W2, b2, W3, h1, S1, h2, G2L, W2T);
    hipLaunchKernelGGL(prep2_kernel, dim3(320), dim3(512), 0, stream,
                       W2T, S1, G2L, G1L, x1, x2, h1, h2, dots);
    hipLaunchKernelGGL(ntk_gemm_kernel, dim3(400), dim3(256), 0, stream,
                       G1L, G2L, P1p, P2p);
    hipLaunchKernelGGL(combine_kernel, dim3(400), dim3(256), 0, stream,
                       P1p, P2p, dots, out);
}

// Round 5
// 101.403 us; speedup vs baseline: 3.4848x; 1.1450x over previous
//
#include <hip/hip_runtime.h>

#define NS 64     // samples per batch
#define D  256    // hidden dims
#define O  10     // output dim

typedef unsigned short u16;
typedef __attribute__((ext_vector_type(8))) short bf16x8;   // 8 bf16 = 4 VGPRs
typedef __attribute__((ext_vector_type(4))) float f32x4;

__device__ __forceinline__ u16 f2bf(float f) {
    union { float f; unsigned u; } v; v.f = f;
    unsigned r = v.u + 0x7FFFu + ((v.u >> 16) & 1u);   // RNE
    return (u16)(r >> 16);
}
__device__ __forceinline__ float bf2f(u16 h) {
    union { unsigned u; float f; } v; v.u = ((unsigned)h) << 16;
    return v.f;
}

// ---------------- prep1: forward passes (blocks 0..127, 512 thr, k-split-2)
// ----------------        + W2 transpose (blocks 128..191) ----------------------
__global__ __launch_bounds__(512) void prep1_kernel(
    const float* __restrict__ x1, const float* __restrict__ x2,
    const float* __restrict__ W1, const float* __restrict__ b1,
    const float* __restrict__ W2, const float* __restrict__ b2,
    const float* __restrict__ W3,
    float* __restrict__ h1o, float* __restrict__ S1o,
    float* __restrict__ h2o, u16* __restrict__ G2b,
    float* __restrict__ W2T)
{
    int t = threadIdx.x;
    if (blockIdx.x >= 128) {
        // W2 transpose: 64 blocks, 32x32 tiles, 512 threads (16 rows/pass x 2)
        int blk = blockIdx.x - 128;
        int bxT = blk & 7, byT = blk >> 3;
        __shared__ float tile[32][33];
        int txT = t & 31, tyT = t >> 5;        // tyT 0..15
        #pragma unroll
        for (int r = 0; r < 2; ++r)
            tile[tyT + 16 * r][txT] = W2[(byT * 32 + tyT + 16 * r) * D + bxT * 32 + txT];
        __syncthreads();
        #pragma unroll
        for (int r = 0; r < 2; ++r)
            W2T[(bxT * 32 + tyT + 16 * r) * D + byT * 32 + txT] = tile[txT][tyT + 16 * r];
        return;
    }

    // forward: 1 sample per block, 512 threads = (half k-range) x (256 outputs)
    int s = blockIdx.x;
    const float* x = (s < NS) ? (x1 + s * D) : (x2 + (s - NS) * D);
    int tt = t & 255, half = t >> 8;
    int k0 = half * 128;
    __shared__ float xs[D];
    __shared__ float hs[D];
    __shared__ float part[2][D];

    if (half == 0) xs[tt] = x[tt];
    __syncthreads();

    float acc = half ? 0.0f : b1[tt];
    #pragma unroll 8
    for (int k = 0; k < 128; ++k) acc = fmaf(xs[k0 + k], W1[(k0 + k) * D + tt], acc);
    part[half][tt] = acc;
    __syncthreads();

    if (half == 0) {
        float h1v = tanhf(part[0][tt] + part[1][tt]);
        h1o[s * D + tt] = h1v;
        S1o[s * D + tt] = 1.0f - h1v * h1v;
        hs[tt] = h1v;
    }
    __syncthreads();

    acc = half ? 0.0f : b2[tt];
    #pragma unroll 8
    for (int k = 0; k < 128; ++k) acc = fmaf(hs[k0 + k], W2[(k0 + k) * D + tt], acc);
    part[half][tt] = acc;
    __syncthreads();

    if (half == 0) {
        float h2v = tanhf(part[0][tt] + part[1][tt]);
        h2o[s * D + tt] = h2v;
        hs[tt] = 1.0f - h2v * h2v;             // reuse hs for s2 (all hs reads done)
    }
    __syncthreads();

    // G2 in [s][a][i] layout, bf16 (K-contiguous rows for the MFMA); all 512 threads
    for (int idx = t; idx < O * D; idx += 512) {
        int a = idx >> 8, i = idx & 255;
        G2b[(s * O + a) * D + i] = f2bf(hs[i] * W3[i * O + a]);
    }
}

// ---------------- prep2: backward G1 (blocks 0..127, 512 thr, j-split-2)
// ----------------        + dot matrices (blocks 128..319) ----------------------
__global__ __launch_bounds__(512) void prep2_kernel(
    const float* __restrict__ W2T, const float* __restrict__ S1,
    const u16* __restrict__ G2b, u16* __restrict__ G1b,
    const float* __restrict__ x1, const float* __restrict__ x2,
    const float* __restrict__ h1, const float* __restrict__ h2,
    float* __restrict__ dots)
{
    int t = threadIdx.x;
    if (blockIdx.x < 128) {
        int s = blockIdx.x;
        __shared__ float g2s[O * D];           // [a][j] fp32-expanded, 10 KB
        __shared__ float red[O * D];           // half-1 partials, 10 KB
        for (int idx = t; idx < D * O; idx += 512) g2s[idx] = bf2f(G2b[s * D * O + idx]);
        __syncthreads();

        int tt = t & 255, half = t >> 8;
        int j0 = half * 128;
        float acc[O];
        #pragma unroll
        for (int a = 0; a < O; ++a) acc[a] = 0.0f;
        // j-loop vectorized: g2 via ds_read_b128 (4 j at once) -> ~2x lower LDS issue
        #pragma unroll 2
        for (int j = 0; j < 128; j += 4) {
            float w0 = W2T[(j0 + j + 0) * D + tt];  // coalesced across tt
            float w1 = W2T[(j0 + j + 1) * D + tt];
            float w2 = W2T[(j0 + j + 2) * D + tt];
            float w3 = W2T[(j0 + j + 3) * D + tt];
            #pragma unroll
            for (int a = 0; a < O; ++a) {
                float4 g = *(const float4*)&g2s[a * D + j0 + j];
                acc[a] = fmaf(w0, g.x, acc[a]);
                acc[a] = fmaf(w1, g.y, acc[a]);
                acc[a] = fmaf(w2, g.z, acc[a]);
                acc[a] = fmaf(w3, g.w, acc[a]);
            }
        }
        if (half == 1) {
            #pragma unroll
            for (int a = 0; a < O; ++a) red[a * D + tt] = acc[a];
        }
        __syncthreads();
        if (half == 0) {
            float s1 = S1[s * D + tt];
            #pragma unroll
            for (int a = 0; a < O; ++a)
                G1b[(s * O + a) * D + tt] = f2bf(s1 * (acc[a] + red[a * D + tt]));
        }
        return;
    }

    // dots: 192 blocks: which = idx>>6, n = idx&63; 8 waves per block
    int idx = blockIdx.x - 128;
    int which = idx >> 6, n = idx & 63;
    const float* A; const float* B;
    if (which == 0)      { A = x1 + n * D; B = x2; }
    else if (which == 1) { A = h1 + n * D; B = h1 + NS * D; }
    else                 { A = h2 + n * D; B = h2 + NS * D; }
    __shared__ float as[D];
    if (t < D) as[t] = A[t];
    __syncthreads();
    int wave = t >> 6, lane = t & 63;
    for (int m = wave; m < NS; m += 8) {
        const float* Bv = B + m * D;
        float v = as[lane] * Bv[lane]
                + as[64 + lane] * Bv[64 + lane]
                + as[128 + lane] * Bv[128 + lane]
                + as[192 + lane] * Bv[192 + lane];
        #pragma unroll
        for (int off = 32; off > 0; off >>= 1) v += __shfl_xor(v, off);
        if (lane == 0) dots[(which * NS + n) * NS + m] = v;
    }
}

// ---------------- dual 640x640x256 bf16 MFMA GEMM + direct NTK epilogue --------
// 1600 blocks x 64 thr (1 wave = one 16x16 output tile). No LDS, no K-split:
// A-frag:  lane l reads G[R0 + (l&15)][k=(l>>4)*8 ..+7]   (contiguous 16 B)
// B-frag:  lane l reads G[640 + C0 + (l&15)][same k]      (B^T via fragment layout)
// D[r]:    row = R0 + (l>>4)*4 + r, col = C0 + (l&15)     (m89-verified C/D map)
__global__ __launch_bounds__(64) void ntk_mfma_kernel(
    const u16* __restrict__ G1b, const u16* __restrict__ G2b,
    const float* __restrict__ dots, float* __restrict__ out)
{
    int lane = threadIdx.x;
    int by = blockIdx.x / 40, bx = blockIdx.x % 40;   // 40x40 grid of 16x16 tiles
    int R0 = by * 16, C0 = bx * 16;
    int lm = lane & 15;
    int lk = (lane >> 4) * 8;

    const u16* a1p = G1b + (R0 + lm) * D + lk;
    const u16* b1p = G1b + (640 + C0 + lm) * D + lk;
    const u16* a2p = G2b + (R0 + lm) * D + lk;
    const u16* b2p = G2b + (640 + C0 + lm) * D + lk;

    f32x4 acc1 = {0.f, 0.f, 0.f, 0.f}, acc2 = {0.f, 0.f, 0.f, 0.f};
    #pragma unroll
    for (int ks = 0; ks < 8; ++ks) {
        bf16x8 a1 = *(const bf16x8*)(a1p + ks * 32);
        bf16x8 b1 = *(const bf16x8*)(b1p + ks * 32);
        bf16x8 a2 = *(const bf16x8*)(a2p + ks * 32);
        bf16x8 b2 = *(const bf16x8*)(b2p + ks * 32);
        acc1 = __builtin_amdgcn_mfma_f32_16x16x32_bf16(a1, b1, acc1, 0, 0, 0);
        acc2 = __builtin_amdgcn_mfma_f32_16x16x32_bf16(a2, b2, acc2, 0, 0, 0);
    }

    // epilogue: out[n,m,a,b] = cx*P1 + ch1*P2 + (a==b)*(1+ch2)
    int C = C0 + lm;
    int m = C / 10, b = C - m * 10;
    #pragma unroll
    for (int r = 0; r < 4; ++r) {
        int R = R0 + (lane >> 4) * 4 + r;
        int n = R / 10, a = R - n * 10;
        float cx  = 1.0f + dots[0 * NS * NS + n * NS + m];
        float ch1 = 1.0f + dots[1 * NS * NS + n * NS + m];
        float val = cx * acc1[r] + ch1 * acc2[r];
        if (a == b) val += 1.0f + dots[2 * NS * NS + n * NS + m];
        out[(n * NS + m) * (O * O) + a * O + b] = val;
    }
}

extern "C" void kernel_launch(void* const* d_in, const int* in_sizes, int n_in,
                              void* d_out, int out_size, void* d_ws, size_t ws_size,
                              hipStream_t stream) {
    const float* x1 = (const float*)d_in[0];
    const float* x2 = (const float*)d_in[1];
    const float* W1 = (const float*)d_in[2];
    const float* b1 = (const float*)d_in[3];
    const float* W2 = (const float*)d_in[4];
    const float* b2 = (const float*)d_in[5];
    const float* W3 = (const float*)d_in[6];
    // b3 (d_in[7]) does not enter the Jacobian.

    float* ws   = (float*)d_ws;
    float* h1   = ws;                     // 128*256
    float* S1   = h1 + 128 * D;           // 128*256
    float* h2   = S1 + 128 * D;           // 128*256
    float* W2T  = h2 + 128 * D;           // 256*256
    float* dots = W2T + D * D;            // 3*64*64
    u16*  G2b   = (u16*)(dots + 3 * NS * NS);  // 1280*256 bf16 (16B-aligned offset)
    u16*  G1b   = G2b + 1280 * D;              // 1280*256 bf16
    float* out  = (float*)d_out;

    hipLaunchKernelGGL(prep1_kernel, dim3(192), dim3(512), 0, stream,
                       x1, x2, W1, b1, W2, b2, W3, h1, S1, h2, G2b, W2T);
    hipLaunchKernelGGL(prep2_kernel, dim3(320), dim3(512), 0, stream,
                       W2T, S1, G2b, G1b, x1, x2, h1, h2, dots);
    hipLaunchKernelGGL(ntk_mfma_kernel, dim3(1600), dim3(64), 0, stream,
                       G1b, G2b, dots, out);
}